// Round 6
// baseline (229.841 us; speedup 1.0000x reference)
//
#include <hip/hip_runtime.h>
#include <math.h>

#define BB   4
#define SS   4096
#define DD   1024
#define BL   128
#define NB   32

typedef __attribute__((ext_vector_type(4))) float f32x4;
typedef __attribute__((ext_vector_type(16))) float f32x16;
typedef __attribute__((ext_vector_type(8))) short bf16x8;
typedef __attribute__((ext_vector_type(8))) unsigned short u16x8;

__device__ __forceinline__ float bf2f(unsigned short u) {
    return __uint_as_float(((unsigned int)u) << 16);
}
__device__ __forceinline__ unsigned short f2bf(float f) {
    unsigned int u = __float_as_uint(f);
    return (unsigned short)((u + 0x7FFFu + ((u >> 16) & 1u)) >> 16);  // RNE
}
__device__ __forceinline__ void gload_lds16(const unsigned short* g, unsigned short* l) {
    __builtin_amdgcn_global_load_lds(
        (const __attribute__((address_space(1))) void*)g,
        (__attribute__((address_space(3))) void*)l, 16, 0, 0);
}

// ---------------- fp32 -> bf16 elementwise ----------------
__global__ __launch_bounds__(256) void cvt_f32_bf16(const float4* __restrict__ in,
                                                    ushort4* __restrict__ out, int n4) {
    int i = blockIdx.x * 256 + threadIdx.x;
    if (i < n4) {
        float4 v = in[i];
        ushort4 o;
        o.x = f2bf(v.x); o.y = f2bf(v.y); o.z = f2bf(v.z); o.w = f2bf(v.w);
        out[i] = o;
    }
}

// ---------------- transpose + convert: W[K][N] f32 -> WT[N][K] bf16 ----------------
__global__ __launch_bounds__(256) void transcvt(const float* __restrict__ W,
                                                unsigned short* __restrict__ WT,
                                                int K, int N) {
    __shared__ float tile[32][33];
    const int n0 = blockIdx.x * 32, k0 = blockIdx.y * 32;
    const int tx = threadIdx.x & 31, ty = threadIdx.x >> 5;  // ty 0..7
    #pragma unroll
    for (int r = 0; r < 32; r += 8)
        tile[ty + r][tx] = W[(size_t)(k0 + ty + r) * N + n0 + tx];
    __syncthreads();
    #pragma unroll
    for (int r = 0; r < 32; r += 8)
        WT[(size_t)(n0 + ty + r) * K + k0 + tx] = f2bf(tile[tx][ty + r]);
}

// ---------------- 256x256 8-phase bf16 MFMA GEMM (32x32x16): C = A @ BT^T + bias ----------------
// A: [M][K] bf16 row-major; BT: [N][K] bf16; C: [M][N] OutT.
// BK=64, 512 threads = 8 waves (2M x 4N). Per wave: 128x64 out = 4 M-frags x 2 N-frags (32x32).
// LDS: 2 dbuf x (256x64) A + B in one 128 KiB arena, XOR-swizzled in 16B chunks.
// Phase q computes M-frag q (8 MFMA); stage plan + vmcnt cadence identical to round-4 kernel.

#define GBAR() __builtin_amdgcn_s_barrier()
#define LGKM0() do { asm volatile("s_waitcnt lgkmcnt(0)" ::: "memory"); \
                     __builtin_amdgcn_sched_barrier(0); } while (0)

#define MFMA_K32(q, kk) \
    acc[q][0] = __builtin_amdgcn_mfma_f32_32x32x16_bf16(a[kk], breg[0][kk], acc[q][0], 0, 0, 0); \
    acc[q][1] = __builtin_amdgcn_mfma_f32_32x32x16_bf16(a[kk], breg[1][kk], acc[q][1], 0, 0, 0);

#define MFMA_Q(q) do { \
    __builtin_amdgcn_s_setprio(1); \
    MFMA_K32(q, 0) MFMA_K32(q, 1) MFMA_K32(q, 2) MFMA_K32(q, 3) \
    __builtin_amdgcn_s_setprio(0); } while (0)

#define LOAD_A(q) do { \
    a[0] = *(const bf16x8*)(pA + (q)*2048 + swk0); \
    a[1] = *(const bf16x8*)(pA + (q)*2048 + swk1); \
    a[2] = *(const bf16x8*)(pA + (q)*2048 + swk2); \
    a[3] = *(const bf16x8*)(pA + (q)*2048 + swk3); } while (0)

template<typename OutT>
__global__ __launch_bounds__(512, 2) void gemm256(
    const unsigned short* __restrict__ A, const unsigned short* __restrict__ BT,
    const float* __restrict__ bias, OutT* __restrict__ C,
    int M, int N, int K, int ntn)
{
    __shared__ __align__(16) unsigned short smem[65536];   // 128 KiB arena
    unsigned short* sAb = smem;
    unsigned short* sBb = smem + 32768;

    const int nwg = gridDim.x;
    const int wg  = blockIdx.x;
    const int swzb = (wg & 7) * (nwg >> 3) + (wg >> 3);   // bijective: nwg % 8 == 0
    const int m0 = (swzb / ntn) * 256, n0 = (swzb % ntn) * 256;

    const int t    = threadIdx.x;
    const int w    = t >> 6;
    const int lane = t & 63;
    const int wm   = w >> 2, wn = w & 3;

    const int srow8 = lane >> 3;
    const int sgch  = (lane & 7) ^ srow8;     // pre-swizzled global k-chunk
    const int NT    = K >> 6;                 // K-tiles of 64

    auto STAGE_A = [&](int ts, int cb) {
        const int r = cb + (w << 3);
        gload_lds16(A + (size_t)(m0 + r + srow8) * K + (ts << 6) + sgch * 8,
                    sAb + (size_t)(ts & 1) * 16384 + r * 64);
    };
    auto STAGE_B = [&](int ts, int cb) {
        const int r = cb + (w << 3);
        gload_lds16(BT + (size_t)(n0 + r + srow8) * K + (ts << 6) + sgch * 8,
                    sBb + (size_t)(ts & 1) * 16384 + r * 64);
    };

    // 32x32x16 fragment addressing: row = base + (lane&31), k = kk*16 + hi*8
    // logical 16B chunk = kk*2 + hi; phys = chunk ^ (row&7) = chunk ^ (lane&7)
    const int hi   = lane >> 5;
    const int frA  = wm * 128 + (lane & 31);
    const int frB  = wn * 64  + (lane & 31);
    const int swk0 = ((0 * 2 + hi) ^ (lane & 7)) * 8;
    const int swk1 = ((1 * 2 + hi) ^ (lane & 7)) * 8;
    const int swk2 = ((2 * 2 + hi) ^ (lane & 7)) * 8;
    const int swk3 = ((3 * 2 + hi) ^ (lane & 7)) * 8;

    f32x16 acc[4][2];
    #pragma unroll
    for (int i = 0; i < 4; ++i) {
        acc[i][0] = (f32x16){};
        acc[i][1] = (f32x16){};
    }

    // ---- prologue: tile 0 fully; tile 1's B + A-lo (6 insts stay in flight) ----
    STAGE_B(0, 0); STAGE_B(0, 64); STAGE_B(0, 128); STAGE_B(0, 192);
    STAGE_A(0, 0); STAGE_A(0, 64); STAGE_A(0, 128); STAGE_A(0, 192);
    asm volatile("s_waitcnt vmcnt(4)" ::: "memory");
    if (NT > 1) {
        STAGE_B(1, 0); STAGE_B(1, 64); STAGE_B(1, 128); STAGE_B(1, 192);
        STAGE_A(1, 0); STAGE_A(1, 128);
        asm volatile("s_waitcnt vmcnt(6)" ::: "memory");
    } else {
        asm volatile("s_waitcnt vmcnt(0)" ::: "memory");
    }
    GBAR();

    for (int ts = 0; ts < NT; ++ts) {
        const unsigned short* pA = sAb + (size_t)(ts & 1) * 16384 + frA * 64;
        const unsigned short* pB = sBb + (size_t)(ts & 1) * 16384 + frB * 64;
        bf16x8 breg[2][4];
        bf16x8 a[4];

        // ---- phase 1: B->regs (8) + A-frag0 (4); stage A-hi(ts+1) ----
        #pragma unroll
        for (int ni = 0; ni < 2; ++ni) {
            breg[ni][0] = *(const bf16x8*)(pB + ni * 2048 + swk0);
            breg[ni][1] = *(const bf16x8*)(pB + ni * 2048 + swk1);
            breg[ni][2] = *(const bf16x8*)(pB + ni * 2048 + swk2);
            breg[ni][3] = *(const bf16x8*)(pB + ni * 2048 + swk3);
        }
        LOAD_A(0);
        if (ts + 1 < NT) { STAGE_A(ts + 1, 64); STAGE_A(ts + 1, 192); }
        GBAR(); LGKM0(); MFMA_Q(0); GBAR();

        // ---- phase 2: A-frag1; stage B-lo(ts+2) ----
        LOAD_A(1);
        if (ts + 2 < NT) { STAGE_B(ts + 2, 0); STAGE_B(ts + 2, 64); }
        GBAR(); LGKM0(); MFMA_Q(1); GBAR();

        // ---- phase 3: A-frag2; stage B-hi(ts+2) ----
        LOAD_A(2);
        if (ts + 2 < NT) { STAGE_B(ts + 2, 128); STAGE_B(ts + 2, 192); }
        GBAR(); LGKM0(); MFMA_Q(2); GBAR();

        // ---- phase 4: A-frag3; stage A-lo(ts+2); counted vmcnt ----
        LOAD_A(3);
        if (ts + 2 < NT) { STAGE_A(ts + 2, 0); STAGE_A(ts + 2, 128); }
        GBAR(); LGKM0(); MFMA_Q(3);
        if (ts + 2 < NT) asm volatile("s_waitcnt vmcnt(6)" ::: "memory");
        else             asm volatile("s_waitcnt vmcnt(0)" ::: "memory");
        GBAR();
    }

    // ---- epilogue: LDS-bounce for coalesced wide stores ----
    // C/D 32x32 layout: col = lane&31, row = (r&3) + 8*(r>>2) + 4*hi
    if constexpr (sizeof(OutT) == 2) {
        unsigned short (*cb)[256] = (unsigned short (*)[256])smem;
        #pragma unroll
        for (int ni = 0; ni < 2; ++ni) {
            const int col = wn * 64 + ni * 32 + (lane & 31);
            const float bv = bias[n0 + col];
            #pragma unroll
            for (int mi = 0; mi < 4; ++mi) {
                const int rb = wm * 128 + mi * 32 + 4 * hi;
                #pragma unroll
                for (int r = 0; r < 16; ++r)
                    cb[rb + (r & 3) + 8 * (r >> 2)][col] = f2bf(acc[mi][ni][r] + bv);
            }
        }
        __syncthreads();
        unsigned short* Cp = (unsigned short*)C;
        #pragma unroll
        for (int it = 0; it < 16; ++it) {
            const int row = it * 16 + (t >> 5);
            const int cs  = (t & 31) * 8;
            u16x8 v = *(const u16x8*)&cb[row][cs];
            *(u16x8*)(Cp + (size_t)(m0 + row) * N + n0 + cs) = v;
        }
    } else {
        float (*cf)[256] = (float (*)[256])smem;
        #pragma unroll
        for (int h = 0; h < 2; ++h) {
            if (wm == h) {
                #pragma unroll
                for (int ni = 0; ni < 2; ++ni) {
                    const int col = wn * 64 + ni * 32 + (lane & 31);
                    const float bv = bias[n0 + col];
                    #pragma unroll
                    for (int mi = 0; mi < 4; ++mi) {
                        const int rb = mi * 32 + 4 * hi;   // 0..127 local
                        #pragma unroll
                        for (int r = 0; r < 16; ++r)
                            cf[rb + (r & 3) + 8 * (r >> 2)][col] = acc[mi][ni][r] + bv;
                    }
                }
            }
            __syncthreads();
            float* Cp = (float*)C;
            #pragma unroll
            for (int it = 0; it < 16; ++it) {
                const int row = it * 8 + (t >> 6);     // 0..127
                const int c4  = (t & 63) * 4;
                float4 v = *(const float4*)&cf[row][c4];
                *(float4*)(Cp + (size_t)(m0 + h * 128 + row) * N + n0 + c4) = v;
            }
            __syncthreads();
        }
    }
}

// ---------------- column attention, MFMA QK^T (bf16 in, bf16 out) ----------------
__global__ __launch_bounds__(256) void col_attn_mfma(const unsigned short* __restrict__ qkv,
                                                     unsigned short* __restrict__ outb)
{
    const int b  = blockIdx.x >> 7;
    const int bl = blockIdx.x & (BL - 1);

    __shared__ float red[4][32][33];
    __shared__ float p_s[NB][NB + 1];

    const int t    = threadIdx.x;
    const int w    = t >> 6;
    const int lane = t & 63;

    const size_t rowstride = (size_t)BL * 3 * DD;
    const unsigned short* base = qkv + ((size_t)b * NB * BL + bl) * (3 * DD);

    // ---- QK^T: wave w covers k in [w*256, w*256+256), 16 MFMA steps ----
    {
        const int arow = lane & 31;
        const int khi  = (lane >> 5) * 8;
        const unsigned short* qp = base + (size_t)arow * rowstride + w * 256 + khi;
        const unsigned short* kp = qp + DD;

        f32x16 acc0 = {}, acc1 = {};
        #pragma unroll
        for (int s = 0; s < 16; s += 2) {
            bf16x8 aq0 = *(const bf16x8*)(qp + s * 16);
            bf16x8 bk0 = *(const bf16x8*)(kp + s * 16);
            bf16x8 aq1 = *(const bf16x8*)(qp + s * 16 + 16);
            bf16x8 bk1 = *(const bf16x8*)(kp + s * 16 + 16);
            acc0 = __builtin_amdgcn_mfma_f32_32x32x16_bf16(aq0, bk0, acc0, 0, 0, 0);
            acc1 = __builtin_amdgcn_mfma_f32_32x32x16_bf16(aq1, bk1, acc1, 0, 0, 0);
        }
        const int ccol = lane & 31;
        const int rhi  = (lane >> 5) * 4;
        #pragma unroll
        for (int r = 0; r < 16; ++r) {
            const int crow = (r & 3) + 8 * (r >> 2) + rhi;
            red[w][crow][ccol] = acc0[r] + acc1[r];
        }
    }
    __syncthreads();

    // ---- reduce 4 waves -> p_s, apply scale ----
    {
        const float scale = 1.0f / 32.0f;   // 1/sqrt(1024)
        const int row = t >> 3;
        const int c0  = (t & 7) * 4;
        #pragma unroll
        for (int j = 0; j < 4; ++j) {
            const int c = c0 + j;
            p_s[row][c] = (red[0][row][c] + red[1][row][c] +
                           red[2][row][c] + red[3][row][c]) * scale;
        }
    }
    __syncthreads();

    // ---- causal softmax (rows on lanes 0..31; tiny) ----
    if (t < NB) {
        const int i = t;
        float mx = p_s[i][0];
        for (int j = 1; j <= i; ++j) mx = fmaxf(mx, p_s[i][j]);
        float sum = 0.f;
        for (int j = 0; j <= i; ++j) { float e = __expf(p_s[i][j] - mx); p_s[i][j] = e; sum += e; }
        const float inv = 1.0f / sum;
        for (int j = 0; j <= i; ++j) p_s[i][j] *= inv;
        for (int j = i + 1; j < NB; ++j) p_s[i][j] = 0.f;
    }
    __syncthreads();

    // ---- PV: thread owns 4 consecutive d for 8 rows per pass (coalesced V reads) ----
    const int d0v = t * 4;
    const unsigned short* vbase = base + 2 * DD;
    #pragma unroll 1
    for (int p = 0; p < 4; ++p) {
        float4 acc[8];
        #pragma unroll
        for (int ii = 0; ii < 8; ++ii) acc[ii] = make_float4(0.f, 0.f, 0.f, 0.f);
        const int jmax = (p + 1) * 8;
        for (int j = 0; j < jmax; ++j) {
            ushort4 v4 = *(const ushort4*)(vbase + (size_t)j * rowstride + d0v);
            const float vx = bf2f(v4.x), vy = bf2f(v4.y), vz = bf2f(v4.z), vw = bf2f(v4.w);
            #pragma unroll
            for (int ii = 0; ii < 8; ++ii) {
                const float pij = p_s[p * 8 + ii][j];
                acc[ii].x += pij * vx;
                acc[ii].y += pij * vy;
                acc[ii].z += pij * vz;
                acc[ii].w += pij * vw;
            }
        }
        #pragma unroll
        for (int ii = 0; ii < 8; ++ii) {
            const int i = p * 8 + ii;
            ushort4 o;
            o.x = f2bf(acc[ii].x); o.y = f2bf(acc[ii].y);
            o.z = f2bf(acc[ii].z); o.w = f2bf(acc[ii].w);
            *(ushort4*)(outb + ((size_t)(b * NB + i) * BL + bl) * DD + d0v) = o;
        }
    }
}

extern "C" void kernel_launch(void* const* d_in, const int* in_sizes, int n_in,
                              void* d_out, int out_size, void* d_ws, size_t ws_size,
                              hipStream_t stream) {
    (void)in_sizes; (void)n_in; (void)out_size; (void)ws_size;
    const float* x    = (const float*)d_in[0];
    const float* Wqkv = (const float*)d_in[1];
    const float* bqkv = (const float*)d_in[2];
    const float* Wout = (const float*)d_in[3];
    const float* bout = (const float*)d_in[4];
    float* out = (float*)d_out;

    char* ws = (char*)d_ws;
    unsigned short* xb    = (unsigned short*)ws;                        // 32 MiB
    unsigned short* WqkvT = (unsigned short*)(ws + ((size_t)32 << 20)); //  6 MiB
    unsigned short* WoutT = (unsigned short*)(ws + ((size_t)38 << 20)); //  2 MiB
    unsigned short* qkvb  = (unsigned short*)(ws + ((size_t)40 << 20)); // 96 MiB
    unsigned short* attnb = (unsigned short*)(ws + ((size_t)136 << 20));// 32 MiB

    const int M = BB * SS;  // 16384

    cvt_f32_bf16<<<dim3((M * DD / 4 + 255) / 256), dim3(256), 0, stream>>>(
        (const float4*)x, (ushort4*)xb, M * DD / 4);
    transcvt<<<dim3(3 * DD / 32, DD / 32), dim3(256), 0, stream>>>(Wqkv, WqkvT, DD, 3 * DD);
    transcvt<<<dim3(DD / 32, DD / 32), dim3(256), 0, stream>>>(Wout, WoutT, DD, DD);

    // QKV = x @ Wqkv + bqkv  (bf16 out): grid 64 x 12 = 768 tiles
    gemm256<unsigned short><<<dim3((M / 256) * (3 * DD / 256)), dim3(512), 0, stream>>>(
        xb, WqkvT, bqkv, qkvb, M, 3 * DD, DD, 3 * DD / 256);

    col_attn_mfma<<<dim3(BB * BL), dim3(256), 0, stream>>>(qkvb, attnb);

    // out = attn @ Wout + bout  (fp32 out): grid 64 x 4 = 256 tiles
    gemm256<float><<<dim3((M / 256) * (DD / 256)), dim3(512), 0, stream>>>(
        attnb, WoutT, bout, out, M, DD, DD, DD / 256);
}